// Round 6
// baseline (409.397 us; speedup 1.0000x reference)
//
#include <hip/hip_runtime.h>

// Born-series scattering, fully fused recompute-G approach.
// M=4096 pts, 4 wavenumbers (0.5,1,1.5,2), 5 Born iterations, 64 obs dirs.
// R4: bit-faithful D^2 (Gram rounding sequence) -> absmax 0.0.
// R5: fast-math body (rsqrt, native sincos) -> latency-bound, VALUBusy 46%.
// R6: TLP/ILP push: 2048 blocks (256 chunks x 16 cols, 8 row-groups) = 8
//     blocks/CU; unroll 4 -> 8 independent chains/thread; CGREEN folded into
//     stored amplitude (scale = invD, far-field epilogue sign-only).
//
// ws layout (floats):
//   colpack[M][12]: x,y,z,r2, ar[4], ai[4]          (a = C * vw * psi, per k)
//   cvw[M]                                           (C * V * weights)
//   p0r[4][M], p0i[4][M]                            (incident wave)
//   yr[4][M], yi[4][M]                              (matvec accumulators)

#define MM 4096
#define NK 4
#define CGREEN 0.07957747154594767f   // 1/(4*pi)
#define TCOLS 16

#define OFF_VW  49152
#define OFF_P0R 53248
#define OFF_P0I 69632
#define OFF_YR  86016
#define OFF_YI  102400

__global__ __launch_bounds__(256) void init_k(const float* __restrict__ V,
                                              const float* __restrict__ pts,
                                              const float* __restrict__ w,
                                              float* __restrict__ ws) {
#pragma clang fp contract(off)
    int i = blockIdx.x * 256 + threadIdx.x;
    float x = pts[3 * i], y = pts[3 * i + 1], z = pts[3 * i + 2];
    float cvw = CGREEN * (V[i] * w[i]);
    // np.sum(pts*pts, axis=1): each square rounded, sequential add, no fma
    float xx = x * x, yy = y * y, zz = z * z;
    float r2 = (xx + yy) + zz;
    float* cp = ws + i * 12;
    cp[0] = x; cp[1] = y; cp[2] = z; cp[3] = r2;
    ws[OFF_VW + i] = cvw;
#pragma unroll
    for (int n = 0; n < NK; n++) {
        float kk = 0.5f * (float)(n + 1);
        float s, c;
        sincosf(kk * z, &s, &c);       // dot_d = pts . (0,0,1) = z
        ws[OFF_P0R + n * MM + i] = c;
        ws[OFF_P0I + n * MM + i] = s;
        cp[4 + n] = cvw * c;
        cp[8 + n] = cvw * s;
        ws[OFF_YR + n * MM + i] = 0.0f;
        ws[OFF_YI + n * MM + i] = 0.0f;
    }
}

__device__ __forceinline__ void body(float rx, float ry, float rz, float rr2,
                                     int rowg, int jg,
                                     float4 A, float4 R, float4 I,
                                     float acc[8]) {
    // ---- bit-faithful D^2 (DO NOT TOUCH: sets the Born spectrum) ----
    float d2;
    {
#pragma clang fp contract(off)
        // K=3 sgemm/XLA dot: acc=0; fma over k in order, x*x rounded first.
        float dot = fmaf(rz, A.z, fmaf(ry, A.y, rx * A.x));
        float r2s = rr2 + A.w;          // rounded add
        float twod = 2.0f * dot;        // exact
        d2 = r2s - twod;                // single rounded subtract, NO fma
    }
    d2 = fmaxf(d2, 1e-12f);             // clip(D2, 1e-12)
    // ---- fast-math from here (proven invisible in bucketed output) ----
    float invD = __frsqrt_rn(d2);       // ~= 1/sqrt(d2); d2>=1e-12 -> invD<=1e6
    float D = d2 * invD;                // sqrt(d2)
    float scale = (rowg == jg) ? 0.0f : invD;   // C folded into amplitudes
    float s1, c1;
    __sincosf(0.5f * D, &s1, &c1);      // native v_sin/v_cos
    float c2 = fmaf(c1, c1, -s1 * s1);  // cos(1.0 D)
    float s2 = 2.0f * c1 * s1;
    float c3 = fmaf(c2, c1, -s2 * s1);  // cos(1.5 D)
    float s3 = fmaf(s2, c1,  c2 * s1);
    float c4 = fmaf(c2, c2, -s2 * s2);  // cos(2.0 D)
    float s4 = 2.0f * c2 * s2;
    // y_r += scale*(c*ar - s*ai); y_i += scale*(c*ai + s*ar)
    acc[0] = fmaf(scale, fmaf(c1, R.x, -s1 * I.x), acc[0]);
    acc[1] = fmaf(scale, fmaf(c1, I.x,  s1 * R.x), acc[1]);
    acc[2] = fmaf(scale, fmaf(c2, R.y, -s2 * I.y), acc[2]);
    acc[3] = fmaf(scale, fmaf(c2, I.y,  s2 * R.y), acc[3]);
    acc[4] = fmaf(scale, fmaf(c3, R.z, -s3 * I.z), acc[4]);
    acc[5] = fmaf(scale, fmaf(c3, I.z,  s3 * R.z), acc[5]);
    acc[6] = fmaf(scale, fmaf(c4, R.w, -s4 * I.w), acc[6]);
    acc[7] = fmaf(scale, fmaf(c4, I.w,  s4 * R.w), acc[7]);
}

// grid: (256 col-chunks of 16, 8 row-groups of 512); block 256; 2 rows/thread.
__global__ __launch_bounds__(256) void matvec_k(float* __restrict__ ws) {
    __shared__ __align__(16) float tile[TCOLS * 12];
    const int chunk = blockIdx.x;
    const int rg = blockIdx.y;
    if (threadIdx.x < TCOLS * 3) {
        ((float4*)tile)[threadIdx.x] =
            ((const float4*)(ws + chunk * (TCOLS * 12)))[threadIdx.x];
    }
    __syncthreads();
    const int r0 = rg * 512 + threadIdx.x;
    const int r1 = r0 + 256;
    const float4 row0 = *(const float4*)&ws[r0 * 12];   // x,y,z,r2
    const float4 row1 = *(const float4*)&ws[r1 * 12];
    float a0[8], a1[8];
#pragma unroll
    for (int i = 0; i < 8; i++) { a0[i] = 0.0f; a1[i] = 0.0f; }
    const int jg0 = chunk * TCOLS;
#pragma unroll 4
    for (int j = 0; j < TCOLS; j++) {
        const float4* cp = (const float4*)&tile[j * 12];
        float4 A = cp[0], R = cp[1], I = cp[2];   // same addr all lanes: LDS broadcast
        body(row0.x, row0.y, row0.z, row0.w, r0, jg0 + j, A, R, I, a0);
        body(row1.x, row1.y, row1.z, row1.w, r1, jg0 + j, A, R, I, a1);
    }
    float* yr = ws + OFF_YR;
    float* yi = ws + OFF_YI;
#pragma unroll
    for (int n = 0; n < NK; n++) {
        atomicAdd(&yr[n * MM + r0], a0[2 * n]);
        atomicAdd(&yi[n * MM + r0], a0[2 * n + 1]);
        atomicAdd(&yr[n * MM + r1], a1[2 * n]);
        atomicAdd(&yi[n * MM + r1], a1[2 * n + 1]);
    }
}

__global__ __launch_bounds__(256) void update_k(float* __restrict__ ws) {
    int i = blockIdx.x * 256 + threadIdx.x;
    float cvw = ws[OFF_VW + i];
#pragma unroll
    for (int n = 0; n < NK; n++) {
        float pr = ws[OFF_P0R + n * MM + i] + ws[OFF_YR + n * MM + i];
        float pi = ws[OFF_P0I + n * MM + i] + ws[OFF_YI + n * MM + i];
        ws[i * 12 + 4 + n] = cvw * pr;
        ws[i * 12 + 8 + n] = cvw * pi;
        ws[OFF_YR + n * MM + i] = 0.0f;
        ws[OFF_YI + n * MM + i] = 0.0f;
    }
}

// one block per (k, obs_dir) pair: 256 blocks.
// a already contains C*vw*psi, so f = -sum a*e^{-ikQ} (no trailing C).
__global__ __launch_bounds__(256) void far_k(const float* __restrict__ obs,
                                             const float* __restrict__ ws,
                                             float* __restrict__ out) {
    int kidx = blockIdx.x >> 6;
    int d = blockIdx.x & 63;
    float kk = 0.5f * (float)(kidx + 1);
    float ox = obs[3 * d], oy = obs[3 * d + 1], oz = obs[3 * d + 2];
    float fr = 0.0f, fi = 0.0f;
    for (int j = threadIdx.x; j < MM; j += 256) {
        const float* c = ws + j * 12;
        float q = fmaf(c[2], oz, fmaf(c[1], oy, c[0] * ox));
        float ar = c[4 + kidx], ai = c[8 + kidx];
        float s, co;
        __sincosf(kk * q, &s, &co);
        // phr = cos(kq), phi = -sin(kq); ir = ar*phr - ai*phi; ii = ar*phi + ai*phr
        fr += fmaf(ar, co,  ai * s);
        fi += fmaf(ai, co, -ar * s);
    }
#pragma unroll
    for (int off = 32; off > 0; off >>= 1) {
        fr += __shfl_down(fr, off);
        fi += __shfl_down(fi, off);
    }
    __shared__ float red[4][2];
    int wave = threadIdx.x >> 6;
    if ((threadIdx.x & 63) == 0) { red[wave][0] = fr; red[wave][1] = fi; }
    __syncthreads();
    if (threadIdx.x == 0) {
        fr = red[0][0] + red[1][0] + red[2][0] + red[3][0];
        fi = red[0][1] + red[1][1] + red[2][1] + red[3][1];
        out[(kidx * 64 + d) * 2 + 0] = -fr;
        out[(kidx * 64 + d) * 2 + 1] = -fi;
    }
}

extern "C" void kernel_launch(void* const* d_in, const int* in_sizes, int n_in,
                              void* d_out, int out_size, void* d_ws, size_t ws_size,
                              hipStream_t stream) {
    const float* V   = (const float*)d_in[0];
    const float* obs = (const float*)d_in[1];
    const float* pts = (const float*)d_in[2];
    const float* w   = (const float*)d_in[3];
    float* ws  = (float*)d_ws;
    float* out = (float*)d_out;

    init_k<<<16, 256, 0, stream>>>(V, pts, w, ws);
    for (int it = 0; it < 5; it++) {
        matvec_k<<<dim3(256, 8), 256, 0, stream>>>(ws);
        update_k<<<16, 256, 0, stream>>>(ws);
    }
    far_k<<<256, 256, 0, stream>>>(obs, ws, out);
}

// Round 7
// 392.691 us; speedup vs baseline: 1.0425x; 1.0425x over previous
//
#include <hip/hip_runtime.h>

// Born-series scattering, fully fused recompute-G approach.
// M=4096 pts, 4 wavenumbers (0.5,1,1.5,2), 5 Born iterations, 64 obs dirs.
// R4: bit-faithful D^2 (Gram rounding sequence) -> absmax 0.0.
// R5: fast-math body (rsqrt, native sincos): 43.5us matvec, atomics suspected.
// R6: 2x chunks -> 2x atomics -> 67us. CONFIRMED: device-scope f32 atomics
//     serialize at the memory-side atomic units (~5.5ns marginal each).
// R7: NO ATOMICS. Each (chunk,rg) block stores private partial sums
//     part[chunk][plane][row] (coalesced plain stores); update_k reduces over
//     chunks in fixed order and computes a = cvw*(p0 + sum). Atomic fallback
//     (C=64) if ws_size too small for the 16MB partial buffer.
//
// ws layout (floats):
//   colpack[M][12]: x,y,z,r2, ar[4], ai[4]          (a = C * vw * psi, per k)
//   cvw[M]                                           (C * V * weights)
//   p0r[4][M], p0i[4][M]                            (incident wave)
//   yr[4][M], yi[4][M]                              (atomic-fallback accums)
//   part[C][8][M]                                    (partial-sum path, 16MB)

#define MM 4096
#define NK 4
#define CGREEN 0.07957747154594767f   // 1/(4*pi)

#define OFF_VW   49152
#define OFF_P0R  53248
#define OFF_P0I  69632
#define OFF_YR   86016
#define OFF_YI   102400
#define OFF_PART 118784
#define PART_FLOATS (128 * 8 * MM)     // C=128 partial buffer
#define WS_NEED_PART ((size_t)(OFF_PART + PART_FLOATS) * 4)

__global__ __launch_bounds__(256) void init_k(const float* __restrict__ V,
                                              const float* __restrict__ pts,
                                              const float* __restrict__ w,
                                              float* __restrict__ ws) {
#pragma clang fp contract(off)
    int i = blockIdx.x * 256 + threadIdx.x;
    float x = pts[3 * i], y = pts[3 * i + 1], z = pts[3 * i + 2];
    float cvw = CGREEN * (V[i] * w[i]);
    // np.sum(pts*pts, axis=1): each square rounded, sequential add, no fma
    float xx = x * x, yy = y * y, zz = z * z;
    float r2 = (xx + yy) + zz;
    float* cp = ws + i * 12;
    cp[0] = x; cp[1] = y; cp[2] = z; cp[3] = r2;
    ws[OFF_VW + i] = cvw;
#pragma unroll
    for (int n = 0; n < NK; n++) {
        float kk = 0.5f * (float)(n + 1);
        float s, c;
        sincosf(kk * z, &s, &c);       // dot_d = pts . (0,0,1) = z
        ws[OFF_P0R + n * MM + i] = c;
        ws[OFF_P0I + n * MM + i] = s;
        cp[4 + n] = cvw * c;
        cp[8 + n] = cvw * s;
        ws[OFF_YR + n * MM + i] = 0.0f;
        ws[OFF_YI + n * MM + i] = 0.0f;
    }
}

__device__ __forceinline__ void body(float rx, float ry, float rz, float rr2,
                                     int rowg, int jg,
                                     float4 A, float4 R, float4 I,
                                     float acc[8]) {
    // ---- bit-faithful D^2 (DO NOT TOUCH: sets the Born spectrum) ----
    float d2;
    {
#pragma clang fp contract(off)
        // K=3 sgemm/XLA dot: acc=0; fma over k in order, x*x rounded first.
        float dot = fmaf(rz, A.z, fmaf(ry, A.y, rx * A.x));
        float r2s = rr2 + A.w;          // rounded add
        float twod = 2.0f * dot;        // exact
        d2 = r2s - twod;                // single rounded subtract, NO fma
    }
    d2 = fmaxf(d2, 1e-12f);             // clip(D2, 1e-12)
    // ---- fast-math from here (proven invisible in bucketed output) ----
    float invD = __builtin_amdgcn_rsqf(d2);   // v_rsq_f32
    float D = d2 * invD;                // sqrt(d2)
    float scale = (rowg == jg) ? 0.0f : invD;   // C folded into amplitudes
    float s1, c1;
    __sincosf(0.5f * D, &s1, &c1);      // native v_sin/v_cos
    float c2 = fmaf(c1, c1, -s1 * s1);  // cos(1.0 D)
    float s2 = 2.0f * c1 * s1;
    float c3 = fmaf(c2, c1, -s2 * s1);  // cos(1.5 D)
    float s3 = fmaf(s2, c1,  c2 * s1);
    float c4 = fmaf(c2, c2, -s2 * s2);  // cos(2.0 D)
    float s4 = 2.0f * c2 * s2;
    // y_r += scale*(c*ar - s*ai); y_i += scale*(c*ai + s*ar)
    acc[0] = fmaf(scale, fmaf(c1, R.x, -s1 * I.x), acc[0]);
    acc[1] = fmaf(scale, fmaf(c1, I.x,  s1 * R.x), acc[1]);
    acc[2] = fmaf(scale, fmaf(c2, R.y, -s2 * I.y), acc[2]);
    acc[3] = fmaf(scale, fmaf(c2, I.y,  s2 * R.y), acc[3]);
    acc[4] = fmaf(scale, fmaf(c3, R.z, -s3 * I.z), acc[4]);
    acc[5] = fmaf(scale, fmaf(c3, I.z,  s3 * R.z), acc[5]);
    acc[6] = fmaf(scale, fmaf(c4, R.w, -s4 * I.w), acc[6]);
    acc[7] = fmaf(scale, fmaf(c4, I.w,  s4 * R.w), acc[7]);
}

// grid: (C chunks, 16 row-groups of 256); block 256; 1 row/thread.
template <int C, bool USE_PART>
__global__ __launch_bounds__(256) void matvec_k(float* __restrict__ ws) {
    constexpr int TC = MM / C;                 // cols per block
    __shared__ __align__(16) float tile[TC * 12];
    const int chunk = blockIdx.x;
    const int rg = blockIdx.y;
    for (int idx = threadIdx.x; idx < TC * 3; idx += 256)
        ((float4*)tile)[idx] = ((const float4*)(ws + chunk * (TC * 12)))[idx];
    __syncthreads();
    const int r0 = rg * 256 + threadIdx.x;
    const float4 row0 = *(const float4*)&ws[r0 * 12];   // x,y,z,r2
    float a0[8];
#pragma unroll
    for (int i = 0; i < 8; i++) a0[i] = 0.0f;
    const int jg0 = chunk * TC;
#pragma unroll 4
    for (int j = 0; j < TC; j++) {
        const float4* cp = (const float4*)&tile[j * 12];
        float4 A = cp[0], R = cp[1], I = cp[2];   // same addr all lanes: LDS broadcast
        body(row0.x, row0.y, row0.z, row0.w, r0, jg0 + j, A, R, I, a0);
    }
    if (USE_PART) {
        float* part = ws + OFF_PART;
#pragma unroll
        for (int p = 0; p < 8; p++)
            part[(chunk * 8 + p) * MM + r0] = a0[p];
    } else {
        float* yr = ws + OFF_YR;
        float* yi = ws + OFF_YI;
#pragma unroll
        for (int n = 0; n < NK; n++) {
            atomicAdd(&yr[n * MM + r0], a0[2 * n]);
            atomicAdd(&yi[n * MM + r0], a0[2 * n + 1]);
        }
    }
}

template <int C, bool USE_PART>
__global__ __launch_bounds__(256) void update_k(float* __restrict__ ws) {
    int i = blockIdx.x * 256 + threadIdx.x;
    float cvw = ws[OFF_VW + i];
    float sr[NK], si[NK];
    if (USE_PART) {
#pragma unroll
        for (int n = 0; n < NK; n++) { sr[n] = 0.0f; si[n] = 0.0f; }
        const float* part = ws + OFF_PART;
        for (int c = 0; c < C; c++) {        // fixed order: deterministic
#pragma unroll
            for (int n = 0; n < NK; n++) {
                sr[n] += part[(c * 8 + 2 * n) * MM + i];
                si[n] += part[(c * 8 + 2 * n + 1) * MM + i];
            }
        }
    } else {
#pragma unroll
        for (int n = 0; n < NK; n++) {
            sr[n] = ws[OFF_YR + n * MM + i];
            si[n] = ws[OFF_YI + n * MM + i];
            ws[OFF_YR + n * MM + i] = 0.0f;
            ws[OFF_YI + n * MM + i] = 0.0f;
        }
    }
#pragma unroll
    for (int n = 0; n < NK; n++) {
        float pr = ws[OFF_P0R + n * MM + i] + sr[n];
        float pi = ws[OFF_P0I + n * MM + i] + si[n];
        ws[i * 12 + 4 + n] = cvw * pr;
        ws[i * 12 + 8 + n] = cvw * pi;
    }
}

// one block per (k, obs_dir) pair: 256 blocks.
// a already contains C*vw*psi, so f = -sum a*e^{-ikQ} (no trailing C).
__global__ __launch_bounds__(256) void far_k(const float* __restrict__ obs,
                                             const float* __restrict__ ws,
                                             float* __restrict__ out) {
    int kidx = blockIdx.x >> 6;
    int d = blockIdx.x & 63;
    float kk = 0.5f * (float)(kidx + 1);
    float ox = obs[3 * d], oy = obs[3 * d + 1], oz = obs[3 * d + 2];
    float fr = 0.0f, fi = 0.0f;
    for (int j = threadIdx.x; j < MM; j += 256) {
        const float* c = ws + j * 12;
        float q = fmaf(c[2], oz, fmaf(c[1], oy, c[0] * ox));
        float ar = c[4 + kidx], ai = c[8 + kidx];
        float s, co;
        __sincosf(kk * q, &s, &co);
        fr += fmaf(ar, co,  ai * s);
        fi += fmaf(ai, co, -ar * s);
    }
#pragma unroll
    for (int off = 32; off > 0; off >>= 1) {
        fr += __shfl_down(fr, off);
        fi += __shfl_down(fi, off);
    }
    __shared__ float red[4][2];
    int wave = threadIdx.x >> 6;
    if ((threadIdx.x & 63) == 0) { red[wave][0] = fr; red[wave][1] = fi; }
    __syncthreads();
    if (threadIdx.x == 0) {
        fr = red[0][0] + red[1][0] + red[2][0] + red[3][0];
        fi = red[0][1] + red[1][1] + red[2][1] + red[3][1];
        out[(kidx * 64 + d) * 2 + 0] = -fr;
        out[(kidx * 64 + d) * 2 + 1] = -fi;
    }
}

extern "C" void kernel_launch(void* const* d_in, const int* in_sizes, int n_in,
                              void* d_out, int out_size, void* d_ws, size_t ws_size,
                              hipStream_t stream) {
    const float* V   = (const float*)d_in[0];
    const float* obs = (const float*)d_in[1];
    const float* pts = (const float*)d_in[2];
    const float* w   = (const float*)d_in[3];
    float* ws  = (float*)d_ws;
    float* out = (float*)d_out;

    init_k<<<16, 256, 0, stream>>>(V, pts, w, ws);
    if (ws_size >= WS_NEED_PART) {
        for (int it = 0; it < 5; it++) {
            matvec_k<128, true><<<dim3(128, 16), 256, 0, stream>>>(ws);
            update_k<128, true><<<16, 256, 0, stream>>>(ws);
        }
    } else {
        for (int it = 0; it < 5; it++) {
            matvec_k<64, false><<<dim3(64, 16), 256, 0, stream>>>(ws);
            update_k<64, false><<<16, 256, 0, stream>>>(ws);
        }
    }
    far_k<<<256, 256, 0, stream>>>(obs, ws, out);
}

// Round 8
// 258.463 us; speedup vs baseline: 1.5840x; 1.5193x over previous
//
#include <hip/hip_runtime.h>

// Born-series scattering, fully fused recompute-G approach.
// M=4096 pts, 4 wavenumbers (0.5,1,1.5,2), 5 Born iterations, 64 obs dirs.
// R4: bit-faithful D^2 (Gram rounding sequence) -> absmax 0.0.
// R5: fast-math body (rsqrt, native sincos): 43.5us matvec (incl. atomics).
// R6: 2x chunks -> 2x atomics -> 67us. Atomics serialize; eliminated in R7.
// R7: partial-sum stores (no atomics): matvec ~22us BUT update_k (16 blocks,
//     16.8MB strided read) became a ~48us latency-bound serial reducer.
// R8: fuse reduce+update into one 128-block kernel: one thread per
//     (plane,row), 128 coalesced independent loads each, writes a=cvw*(p0+sum)
//     directly into colpack. update_k eliminated.
//
// ws layout (floats):
//   colpack[M][12]: x,y,z,r2, ar[4], ai[4]          (a = C * vw * psi, per k)
//   cvw[M]                                           (C * V * weights)
//   p0r[4][M], p0i[4][M]                            (incident wave)
//   yr[4][M], yi[4][M]                              (atomic-fallback accums)
//   part[C][8][M]                                    (partial-sum path, 16MB)

#define MM 4096
#define NK 4
#define CGREEN 0.07957747154594767f   // 1/(4*pi)

#define OFF_VW   49152
#define OFF_P0R  53248
#define OFF_P0I  69632
#define OFF_YR   86016
#define OFF_YI   102400
#define OFF_PART 118784
#define NCHUNK 128
#define PART_FLOATS (NCHUNK * 8 * MM)
#define WS_NEED_PART ((size_t)(OFF_PART + PART_FLOATS) * 4)

__global__ __launch_bounds__(256) void init_k(const float* __restrict__ V,
                                              const float* __restrict__ pts,
                                              const float* __restrict__ w,
                                              float* __restrict__ ws) {
#pragma clang fp contract(off)
    int i = blockIdx.x * 256 + threadIdx.x;
    float x = pts[3 * i], y = pts[3 * i + 1], z = pts[3 * i + 2];
    float cvw = CGREEN * (V[i] * w[i]);
    // np.sum(pts*pts, axis=1): each square rounded, sequential add, no fma
    float xx = x * x, yy = y * y, zz = z * z;
    float r2 = (xx + yy) + zz;
    float* cp = ws + i * 12;
    cp[0] = x; cp[1] = y; cp[2] = z; cp[3] = r2;
    ws[OFF_VW + i] = cvw;
#pragma unroll
    for (int n = 0; n < NK; n++) {
        float kk = 0.5f * (float)(n + 1);
        float s, c;
        sincosf(kk * z, &s, &c);       // dot_d = pts . (0,0,1) = z
        ws[OFF_P0R + n * MM + i] = c;
        ws[OFF_P0I + n * MM + i] = s;
        cp[4 + n] = cvw * c;
        cp[8 + n] = cvw * s;
        ws[OFF_YR + n * MM + i] = 0.0f;
        ws[OFF_YI + n * MM + i] = 0.0f;
    }
}

__device__ __forceinline__ void body(float rx, float ry, float rz, float rr2,
                                     int rowg, int jg,
                                     float4 A, float4 R, float4 I,
                                     float acc[8]) {
    // ---- bit-faithful D^2 (DO NOT TOUCH: sets the Born spectrum) ----
    float d2;
    {
#pragma clang fp contract(off)
        // K=3 sgemm/XLA dot: acc=0; fma over k in order, x*x rounded first.
        float dot = fmaf(rz, A.z, fmaf(ry, A.y, rx * A.x));
        float r2s = rr2 + A.w;          // rounded add
        float twod = 2.0f * dot;        // exact
        d2 = r2s - twod;                // single rounded subtract, NO fma
    }
    d2 = fmaxf(d2, 1e-12f);             // clip(D2, 1e-12)
    // ---- fast-math from here (proven invisible in bucketed output) ----
    float invD = __builtin_amdgcn_rsqf(d2);   // v_rsq_f32
    float D = d2 * invD;                // sqrt(d2)
    float scale = (rowg == jg) ? 0.0f : invD;   // C folded into amplitudes
    float s1, c1;
    __sincosf(0.5f * D, &s1, &c1);      // native v_sin/v_cos
    float c2 = fmaf(c1, c1, -s1 * s1);  // cos(1.0 D)
    float s2 = 2.0f * c1 * s1;
    float c3 = fmaf(c2, c1, -s2 * s1);  // cos(1.5 D)
    float s3 = fmaf(s2, c1,  c2 * s1);
    float c4 = fmaf(c2, c2, -s2 * s2);  // cos(2.0 D)
    float s4 = 2.0f * c2 * s2;
    // y_r += scale*(c*ar - s*ai); y_i += scale*(c*ai + s*ar)
    acc[0] = fmaf(scale, fmaf(c1, R.x, -s1 * I.x), acc[0]);
    acc[1] = fmaf(scale, fmaf(c1, I.x,  s1 * R.x), acc[1]);
    acc[2] = fmaf(scale, fmaf(c2, R.y, -s2 * I.y), acc[2]);
    acc[3] = fmaf(scale, fmaf(c2, I.y,  s2 * R.y), acc[3]);
    acc[4] = fmaf(scale, fmaf(c3, R.z, -s3 * I.z), acc[4]);
    acc[5] = fmaf(scale, fmaf(c3, I.z,  s3 * R.z), acc[5]);
    acc[6] = fmaf(scale, fmaf(c4, R.w, -s4 * I.w), acc[6]);
    acc[7] = fmaf(scale, fmaf(c4, I.w,  s4 * R.w), acc[7]);
}

// grid: (C chunks, 16 row-groups of 256); block 256; 1 row/thread.
template <int C, bool USE_PART>
__global__ __launch_bounds__(256) void matvec_k(float* __restrict__ ws) {
    constexpr int TC = MM / C;                 // cols per block
    __shared__ __align__(16) float tile[TC * 12];
    const int chunk = blockIdx.x;
    const int rg = blockIdx.y;
    for (int idx = threadIdx.x; idx < TC * 3; idx += 256)
        ((float4*)tile)[idx] = ((const float4*)(ws + chunk * (TC * 12)))[idx];
    __syncthreads();
    const int r0 = rg * 256 + threadIdx.x;
    const float4 row0 = *(const float4*)&ws[r0 * 12];   // x,y,z,r2
    float a0[8];
#pragma unroll
    for (int i = 0; i < 8; i++) a0[i] = 0.0f;
    const int jg0 = chunk * TC;
#pragma unroll 4
    for (int j = 0; j < TC; j++) {
        const float4* cp = (const float4*)&tile[j * 12];
        float4 A = cp[0], R = cp[1], I = cp[2];   // same addr all lanes: LDS broadcast
        body(row0.x, row0.y, row0.z, row0.w, r0, jg0 + j, A, R, I, a0);
    }
    if (USE_PART) {
        float* part = ws + OFF_PART;
#pragma unroll
        for (int p = 0; p < 8; p++)
            part[(chunk * 8 + p) * MM + r0] = a0[p];
    } else {
        float* yr = ws + OFF_YR;
        float* yi = ws + OFF_YI;
#pragma unroll
        for (int n = 0; n < NK; n++) {
            atomicAdd(&yr[n * MM + r0], a0[2 * n]);
            atomicAdd(&yi[n * MM + r0], a0[2 * n + 1]);
        }
    }
}

// Fused chunk-reduction + psi update. One thread per (plane, row):
// 32768 threads = 128 blocks x 256. plane p: 2n=real, 2n+1=imag of k-index n.
template <int C>
__global__ __launch_bounds__(256) void reduce_update_k(float* __restrict__ ws) {
    int tid = blockIdx.x * 256 + threadIdx.x;      // [0, 32768)
    int row = tid & (MM - 1);
    int p = tid >> 12;                              // plane 0..7
    const float* part = ws + OFF_PART;
    float s = 0.0f;
    for (int c = 0; c < C; c++)                     // fixed order: deterministic
        s += part[(c * 8 + p) * MM + row];
    int n = p >> 1;
    float cvw = ws[OFF_VW + row];
    if ((p & 1) == 0) {
        float pr = ws[OFF_P0R + n * MM + row] + s;
        ws[row * 12 + 4 + n] = cvw * pr;
    } else {
        float pi = ws[OFF_P0I + n * MM + row] + s;
        ws[row * 12 + 8 + n] = cvw * pi;
    }
}

// atomic-fallback update (only used if ws too small for partials)
__global__ __launch_bounds__(256) void update_fallback_k(float* __restrict__ ws) {
    int i = blockIdx.x * 256 + threadIdx.x;
    float cvw = ws[OFF_VW + i];
#pragma unroll
    for (int n = 0; n < NK; n++) {
        float pr = ws[OFF_P0R + n * MM + i] + ws[OFF_YR + n * MM + i];
        float pi = ws[OFF_P0I + n * MM + i] + ws[OFF_YI + n * MM + i];
        ws[i * 12 + 4 + n] = cvw * pr;
        ws[i * 12 + 8 + n] = cvw * pi;
        ws[OFF_YR + n * MM + i] = 0.0f;
        ws[OFF_YI + n * MM + i] = 0.0f;
    }
}

// one block per (k, obs_dir) pair: 256 blocks.
// a already contains C*vw*psi, so f = -sum a*e^{-ikQ} (no trailing C).
__global__ __launch_bounds__(256) void far_k(const float* __restrict__ obs,
                                             const float* __restrict__ ws,
                                             float* __restrict__ out) {
    int kidx = blockIdx.x >> 6;
    int d = blockIdx.x & 63;
    float kk = 0.5f * (float)(kidx + 1);
    float ox = obs[3 * d], oy = obs[3 * d + 1], oz = obs[3 * d + 2];
    float fr = 0.0f, fi = 0.0f;
    for (int j = threadIdx.x; j < MM; j += 256) {
        const float* c = ws + j * 12;
        float q = fmaf(c[2], oz, fmaf(c[1], oy, c[0] * ox));
        float ar = c[4 + kidx], ai = c[8 + kidx];
        float s, co;
        __sincosf(kk * q, &s, &co);
        fr += fmaf(ar, co,  ai * s);
        fi += fmaf(ai, co, -ar * s);
    }
#pragma unroll
    for (int off = 32; off > 0; off >>= 1) {
        fr += __shfl_down(fr, off);
        fi += __shfl_down(fi, off);
    }
    __shared__ float red[4][2];
    int wave = threadIdx.x >> 6;
    if ((threadIdx.x & 63) == 0) { red[wave][0] = fr; red[wave][1] = fi; }
    __syncthreads();
    if (threadIdx.x == 0) {
        fr = red[0][0] + red[1][0] + red[2][0] + red[3][0];
        fi = red[0][1] + red[1][1] + red[2][1] + red[3][1];
        out[(kidx * 64 + d) * 2 + 0] = -fr;
        out[(kidx * 64 + d) * 2 + 1] = -fi;
    }
}

extern "C" void kernel_launch(void* const* d_in, const int* in_sizes, int n_in,
                              void* d_out, int out_size, void* d_ws, size_t ws_size,
                              hipStream_t stream) {
    const float* V   = (const float*)d_in[0];
    const float* obs = (const float*)d_in[1];
    const float* pts = (const float*)d_in[2];
    const float* w   = (const float*)d_in[3];
    float* ws  = (float*)d_ws;
    float* out = (float*)d_out;

    init_k<<<16, 256, 0, stream>>>(V, pts, w, ws);
    if (ws_size >= WS_NEED_PART) {
        for (int it = 0; it < 5; it++) {
            matvec_k<NCHUNK, true><<<dim3(NCHUNK, 16), 256, 0, stream>>>(ws);
            reduce_update_k<NCHUNK><<<128, 256, 0, stream>>>(ws);
        }
    } else {
        for (int it = 0; it < 5; it++) {
            matvec_k<64, false><<<dim3(64, 16), 256, 0, stream>>>(ws);
            update_fallback_k<<<16, 256, 0, stream>>>(ws);
        }
    }
    far_k<<<256, 256, 0, stream>>>(obs, ws, out);
}

// Round 9
// 223.844 us; speedup vs baseline: 1.8289x; 1.1547x over previous
//
#include <hip/hip_runtime.h>

// Born-series scattering, fully fused recompute-G approach.
// M=4096 pts, 4 wavenumbers (0.5,1,1.5,2), 5 Born iterations, 64 obs dirs.
// R4: bit-faithful D^2 (Gram rounding sequence) -> absmax 0.0.
// R5-R6: atomics serialize (~5.5ns each) -> eliminated.
// R7-R8: partial-sum stores + fused reduce: 215us kernel time.
// R9: (1) columns via wave-uniform global loads -> s_load, no LDS/barrier;
//     (2) packed fp32 (ext_vector float2 complex math -> v_pk_fma_f32);
//     (3) float2-interleaved partials + 8-accumulator MLP reduce on 256 blocks.
//
// ws layout (floats):
//   colpack[M][12]: x,y,z,r2, ar[4], ai[4]          (a = C * vw * psi, per k)
//   cvw[M]                                           (C * V * weights)
//   p0r[4][M], p0i[4][M]                            (incident wave)
//   yr[4][M], yi[4][M]                              (atomic-fallback accums)
//   part[C][4][M] of float2                          (partials, 16MB)

#define MM 4096
#define NK 4
#define CGREEN 0.07957747154594767f   // 1/(4*pi)

#define OFF_VW   49152
#define OFF_P0R  53248
#define OFF_P0I  69632
#define OFF_YR   86016
#define OFF_YI   102400
#define OFF_PART 118784
#define NCHUNK 128
#define PART_FLOATS (NCHUNK * 8 * MM)
#define WS_NEED_PART ((size_t)(OFF_PART + PART_FLOATS) * 4)

typedef float f2 __attribute__((ext_vector_type(2)));

__global__ __launch_bounds__(256) void init_k(const float* __restrict__ V,
                                              const float* __restrict__ pts,
                                              const float* __restrict__ w,
                                              float* __restrict__ ws) {
#pragma clang fp contract(off)
    int i = blockIdx.x * 256 + threadIdx.x;
    float x = pts[3 * i], y = pts[3 * i + 1], z = pts[3 * i + 2];
    float cvw = CGREEN * (V[i] * w[i]);
    // np.sum(pts*pts, axis=1): each square rounded, sequential add, no fma
    float xx = x * x, yy = y * y, zz = z * z;
    float r2 = (xx + yy) + zz;
    float* cp = ws + i * 12;
    cp[0] = x; cp[1] = y; cp[2] = z; cp[3] = r2;
    ws[OFF_VW + i] = cvw;
#pragma unroll
    for (int n = 0; n < NK; n++) {
        float kk = 0.5f * (float)(n + 1);
        float s, c;
        sincosf(kk * z, &s, &c);       // dot_d = pts . (0,0,1) = z
        ws[OFF_P0R + n * MM + i] = c;
        ws[OFF_P0I + n * MM + i] = s;
        cp[4 + n] = cvw * c;
        cp[8 + n] = cvw * s;
        ws[OFF_YR + n * MM + i] = 0.0f;
        ws[OFF_YI + n * MM + i] = 0.0f;
    }
}

__device__ __forceinline__ f2 cmul(f2 a, f2 b) {
    f2 r;
    r.x = fmaf(a.x, b.x, -(a.y * b.y));
    r.y = fmaf(a.x, b.y,  (a.y * b.x));
    return r;
}

__device__ __forceinline__ void body(float rx, float ry, float rz, float rr2,
                                     int rowg, int jg,
                                     float4 A, float4 R, float4 I,
                                     f2 acc[4]) {
    // ---- bit-faithful D^2 (DO NOT TOUCH: sets the Born spectrum) ----
    float d2;
    {
#pragma clang fp contract(off)
        // K=3 sgemm/XLA dot: acc=0; fma over k in order, x*x rounded first.
        float dot = fmaf(rz, A.z, fmaf(ry, A.y, rx * A.x));
        float r2s = rr2 + A.w;          // rounded add
        float twod = 2.0f * dot;        // exact
        d2 = r2s - twod;                // single rounded subtract, NO fma
    }
    d2 = fmaxf(d2, 1e-12f);             // clip(D2, 1e-12)
    // ---- fast-math from here (proven invisible in bucketed output) ----
    float invD = __builtin_amdgcn_rsqf(d2);   // v_rsq_f32
    float D = d2 * invD;                // sqrt(d2)
    float scale = (rowg == jg) ? 0.0f : invD;   // C folded into amplitudes
    float s1, c1;
    __sincosf(0.5f * D, &s1, &c1);      // native v_sin/v_cos
    f2 cs1 = {c1, s1};
    f2 cs2 = cmul(cs1, cs1);            // e^{i 1.0 D}
    f2 cs3 = cmul(cs2, cs1);            // e^{i 1.5 D}
    f2 cs4 = cmul(cs2, cs2);            // e^{i 2.0 D}
    // acc[n] += scale * (cs_n * (R_n + i I_n))   -- packed complex fma
    {
        f2 ri = {R.x, I.x}, sw = {-I.x, R.x};
        f2 t = cs1.x * ri; t += cs1.y * sw; acc[0] += scale * t;
    }
    {
        f2 ri = {R.y, I.y}, sw = {-I.y, R.y};
        f2 t = cs2.x * ri; t += cs2.y * sw; acc[1] += scale * t;
    }
    {
        f2 ri = {R.z, I.z}, sw = {-I.z, R.z};
        f2 t = cs3.x * ri; t += cs3.y * sw; acc[2] += scale * t;
    }
    {
        f2 ri = {R.w, I.w}, sw = {-I.w, R.w};
        f2 t = cs4.x * ri; t += cs4.y * sw; acc[3] += scale * t;
    }
}

// grid: (C chunks, 16 row-groups of 256); block 256; 1 row/thread.
// Columns read via wave-uniform global loads (s_load path) -- no LDS.
template <int C, bool USE_PART>
__global__ __launch_bounds__(256) void matvec_k(float* __restrict__ ws) {
    constexpr int TC = MM / C;                 // cols per block
    const int chunk = blockIdx.x;
    const int rg = blockIdx.y;
    const int r0 = rg * 256 + threadIdx.x;
    const float4 row0 = *(const float4*)&ws[r0 * 12];   // x,y,z,r2 (48B-aligned)
    f2 acc[4];
#pragma unroll
    for (int i = 0; i < 4; i++) { acc[i].x = 0.0f; acc[i].y = 0.0f; }
    const int jg0 = chunk * TC;
    const float* colbase = ws + (size_t)jg0 * 12;   // uniform across lanes
#pragma unroll 4
    for (int j = 0; j < TC; j++) {
        const float4* cp = (const float4*)(colbase + j * 12);
        float4 A = cp[0], R = cp[1], I = cp[2];     // wave-uniform -> SGPRs
        body(row0.x, row0.y, row0.z, row0.w, r0, jg0 + j, A, R, I, acc);
    }
    if (USE_PART) {
        f2* part2 = (f2*)(ws + OFF_PART);
#pragma unroll
        for (int n = 0; n < NK; n++)
            part2[(size_t)(chunk * 4 + n) * MM + r0] = acc[n];
    } else {
        float* yr = ws + OFF_YR;
        float* yi = ws + OFF_YI;
#pragma unroll
        for (int n = 0; n < NK; n++) {
            atomicAdd(&yr[n * MM + r0], acc[n].x);
            atomicAdd(&yi[n * MM + r0], acc[n].y);
        }
    }
}

// Fused chunk-reduction + psi update. One thread per (k-index n, row):
// 16384 threads = 256 blocks x 64; 8 independent f2 accumulators for MLP.
template <int C>
__global__ __launch_bounds__(64) void reduce_update_k(float* __restrict__ ws) {
    int tid = blockIdx.x * 64 + threadIdx.x;       // [0, 16384)
    int row = tid & (MM - 1);
    int n = tid >> 12;                              // 0..3
    const f2* part2 = (const f2*)(ws + OFF_PART);
    f2 s[8];
#pragma unroll
    for (int u = 0; u < 8; u++) { s[u].x = 0.0f; s[u].y = 0.0f; }
    for (int c = 0; c < C; c += 8) {
#pragma unroll
        for (int u = 0; u < 8; u++)
            s[u] += part2[(size_t)((c + u) * 4 + n) * MM + row];
    }
    f2 t = ((s[0] + s[1]) + (s[2] + s[3])) + ((s[4] + s[5]) + (s[6] + s[7]));
    float cvw = ws[OFF_VW + row];
    float pr = ws[OFF_P0R + n * MM + row] + t.x;
    float pi = ws[OFF_P0I + n * MM + row] + t.y;
    ws[row * 12 + 4 + n] = cvw * pr;
    ws[row * 12 + 8 + n] = cvw * pi;
}

// atomic-fallback update (only used if ws too small for partials)
__global__ __launch_bounds__(256) void update_fallback_k(float* __restrict__ ws) {
    int i = blockIdx.x * 256 + threadIdx.x;
    float cvw = ws[OFF_VW + i];
#pragma unroll
    for (int n = 0; n < NK; n++) {
        float pr = ws[OFF_P0R + n * MM + i] + ws[OFF_YR + n * MM + i];
        float pi = ws[OFF_P0I + n * MM + i] + ws[OFF_YI + n * MM + i];
        ws[i * 12 + 4 + n] = cvw * pr;
        ws[i * 12 + 8 + n] = cvw * pi;
        ws[OFF_YR + n * MM + i] = 0.0f;
        ws[OFF_YI + n * MM + i] = 0.0f;
    }
}

// one block per (k, obs_dir) pair: 256 blocks.
// a already contains C*vw*psi, so f = -sum a*e^{-ikQ} (no trailing C).
__global__ __launch_bounds__(256) void far_k(const float* __restrict__ obs,
                                             const float* __restrict__ ws,
                                             float* __restrict__ out) {
    int kidx = blockIdx.x >> 6;
    int d = blockIdx.x & 63;
    float kk = 0.5f * (float)(kidx + 1);
    float ox = obs[3 * d], oy = obs[3 * d + 1], oz = obs[3 * d + 2];
    float fr = 0.0f, fi = 0.0f;
    for (int j = threadIdx.x; j < MM; j += 256) {
        const float* c = ws + j * 12;
        float q = fmaf(c[2], oz, fmaf(c[1], oy, c[0] * ox));
        float ar = c[4 + kidx], ai = c[8 + kidx];
        float s, co;
        __sincosf(kk * q, &s, &co);
        fr += fmaf(ar, co,  ai * s);
        fi += fmaf(ai, co, -ar * s);
    }
#pragma unroll
    for (int off = 32; off > 0; off >>= 1) {
        fr += __shfl_down(fr, off);
        fi += __shfl_down(fi, off);
    }
    __shared__ float red[4][2];
    int wave = threadIdx.x >> 6;
    if ((threadIdx.x & 63) == 0) { red[wave][0] = fr; red[wave][1] = fi; }
    __syncthreads();
    if (threadIdx.x == 0) {
        fr = red[0][0] + red[1][0] + red[2][0] + red[3][0];
        fi = red[0][1] + red[1][1] + red[2][1] + red[3][1];
        out[(kidx * 64 + d) * 2 + 0] = -fr;
        out[(kidx * 64 + d) * 2 + 1] = -fi;
    }
}

extern "C" void kernel_launch(void* const* d_in, const int* in_sizes, int n_in,
                              void* d_out, int out_size, void* d_ws, size_t ws_size,
                              hipStream_t stream) {
    const float* V   = (const float*)d_in[0];
    const float* obs = (const float*)d_in[1];
    const float* pts = (const float*)d_in[2];
    const float* w   = (const float*)d_in[3];
    float* ws  = (float*)d_ws;
    float* out = (float*)d_out;

    init_k<<<16, 256, 0, stream>>>(V, pts, w, ws);
    if (ws_size >= WS_NEED_PART) {
        for (int it = 0; it < 5; it++) {
            matvec_k<NCHUNK, true><<<dim3(NCHUNK, 16), 256, 0, stream>>>(ws);
            reduce_update_k<NCHUNK><<<256, 64, 0, stream>>>(ws);
        }
    } else {
        for (int it = 0; it < 5; it++) {
            matvec_k<64, false><<<dim3(64, 16), 256, 0, stream>>>(ws);
            update_fallback_k<<<16, 256, 0, stream>>>(ws);
        }
    }
    far_k<<<256, 256, 0, stream>>>(obs, ws, out);
}